// Round 1
// baseline (261.564 us; speedup 1.0000x reference)
//
#include <hip/hip_runtime.h>

// Problem: B=32, T=256, D=64
//   out[0, t, b, p, q] = r_p*r_q + i_p*i_q   (real part)
//   out[1, t, b, p, q] = i_p*r_q - r_p*i_q   (imag part)
// where r[p] = real[b, t, p], i[p] = imag[b, t, p].
// Write-BW-bound: 256 MiB output vs 4 MiB input. One block per (t,b).

namespace {
constexpr int kB = 32;
constexpr int kT = 256;
constexpr int kD = 64;
constexpr int kDD = kD * kD;          // 4096 floats per (t,b) per part
}

__global__ __launch_bounds__(256) void qouter_kernel(
    const float* __restrict__ real,
    const float* __restrict__ imag,
    float* __restrict__ out) {
    const int blk = blockIdx.x;       // 0 .. T*B-1
    const int t = blk / kB;
    const int b = blk % kB;

    __shared__ float sr[kD];
    __shared__ float si[kD];

    const int tid = threadIdx.x;
    // input layout: real[b, t, p] -> real[(b*T + t)*D + p]
    const int in_base = (b * kT + t) * kD;
    if (tid < kD) {
        sr[tid] = real[in_base + tid];
    } else if (tid < 2 * kD) {
        si[tid - kD] = imag[in_base + (tid - kD)];
    }
    __syncthreads();

    // output layout: out[part, t, b, p, q]
    const size_t base_r = ((size_t)t * kB + b) * kDD;
    const size_t base_i = base_r + (size_t)kT * kB * kDD;
    float4* __restrict__ outr = (float4*)(out + base_r);
    float4* __restrict__ outi = (float4*)(out + base_i);
    const float4* __restrict__ sr4 = (const float4*)sr;
    const float4* __restrict__ si4 = (const float4*)si;

    // 1024 float4 per part, 256 threads -> 4 iterations
#pragma unroll
    for (int k = 0; k < 4; ++k) {
        const int idx = tid + k * 256;    // 0..1023
        const int p = idx >> 4;           // row (p)
        const int j = idx & 15;           // float4 index within q-row
        const float rp = sr[p];
        const float ip = si[p];
        const float4 rq = sr4[j];
        const float4 iq = si4[j];
        float4 vr, vi;
        vr.x = rp * rq.x + ip * iq.x;
        vr.y = rp * rq.y + ip * iq.y;
        vr.z = rp * rq.z + ip * iq.z;
        vr.w = rp * rq.w + ip * iq.w;
        vi.x = ip * rq.x - rp * iq.x;
        vi.y = ip * rq.y - rp * iq.y;
        vi.z = ip * rq.z - rp * iq.z;
        vi.w = ip * rq.w - rp * iq.w;
        outr[idx] = vr;
        outi[idx] = vi;
    }
}

extern "C" void kernel_launch(void* const* d_in, const int* in_sizes, int n_in,
                              void* d_out, int out_size, void* d_ws, size_t ws_size,
                              hipStream_t stream) {
    const float* real = (const float*)d_in[0];
    const float* imag = (const float*)d_in[1];
    float* out = (float*)d_out;
    qouter_kernel<<<kT * kB, 256, 0, stream>>>(real, imag, out);
}